// Round 9
// baseline (182.999 us; speedup 1.0000x reference)
//
#include <hip/hip_runtime.h>
#include <hip/hip_bf16.h>

#define NROWS 65536
#define DIM   256
#define NCLS  1000
#define CPAD  1024

typedef __attribute__((ext_vector_type(8))) short bf16x8;   // 8 bf16 = 4 VGPR
typedef __attribute__((ext_vector_type(4))) float f32x4;    // MFMA C/D

// RTNE float -> bf16 bit pattern (finite inputs only)
__device__ inline unsigned short f2bf(float x) {
    unsigned int u = __builtin_bit_cast(unsigned int, x);
    unsigned int lsb = (u >> 16) & 1u;
    u += 0x7fffu + lsb;
    return (unsigned short)(u >> 16);
}

__device__ inline float bf2f(unsigned short u) {
    unsigned int v = ((unsigned int)u) << 16;
    return __builtin_bit_cast(float, v);
}

// async global->LDS, 16 B per lane, dst = wave-uniform base + lane*16
__device__ inline void gload_lds16(const void* g, void* l) {
    __builtin_amdgcn_global_load_lds(
        (const __attribute__((address_space(1))) unsigned int*)g,
        (__attribute__((address_space(3))) unsigned int*)l, 16, 0, 0);
}

// K1: 8 rows per wave, 4-row batched pipeline: 4 loads in flight,
// 4 interleaved shuffle-reduce chains, 4 stores. 2048 blocks.
__global__ __launch_bounds__(256) void k_norm_acc(
    const float* __restrict__ emb, unsigned short* __restrict__ e,
    float* __restrict__ acc, unsigned int* __restrict__ done)
{
    const int tid = threadIdx.x;
    if (blockIdx.x == 0 && tid == 0) { *acc = 0.0f; *done = 0u; }
    const int wave = tid >> 6, lane = tid & 63;
    const int w = blockIdx.x * 4 + wave;          // 8192 waves, 8 rows each

    #pragma unroll
    for (int i = 0; i < 2; ++i) {
        const int rbase = w * 8 + i * 4;
        float4 v[4];
        #pragma unroll
        for (int r = 0; r < 4; ++r)
            v[r] = ((const float4*)(emb + (size_t)(rbase + r) * DIM))[lane];
        float ss[4];
        #pragma unroll
        for (int r = 0; r < 4; ++r)
            ss[r] = v[r].x*v[r].x + v[r].y*v[r].y + v[r].z*v[r].z + v[r].w*v[r].w;
        #pragma unroll
        for (int off = 1; off < 64; off <<= 1) {
            #pragma unroll
            for (int r = 0; r < 4; ++r) ss[r] += __shfl_xor(ss[r], off);
        }
        #pragma unroll
        for (int r = 0; r < 4; ++r) {
            float inv = 1.0f / fmaxf(sqrtf(ss[r]), 1e-12f);
            ushort4 u;
            u.x = f2bf(v[r].x * inv); u.y = f2bf(v[r].y * inv);
            u.z = f2bf(v[r].z * inv); u.w = f2bf(v[r].w * inv);
            ((ushort4*)(e + (size_t)(rbase + r) * DIM))[lane] = u;
        }
    }
}

// K2: one block per class PAIR (512 blocks): ballot-scan labels once,
// two ballots per batch; wave-cooperative row gathers; count+mean+norm+store.
__global__ __launch_bounds__(256) void k_gather_centers(
    const unsigned short* __restrict__ e, const int* __restrict__ labels,
    unsigned short* __restrict__ cs)
{
    const int c0  = 2 * blockIdx.x, c1 = c0 + 1;   // c0 even; c0<NCLS => c1<=999
    const int tid = threadIdx.x;
    const int wave = tid >> 6, lane = tid & 63;

    if (c0 >= NCLS) {                  // both phantom: zero 2 rows (1 KB)
        if (tid < 64) ((uint4*)(cs + (size_t)c0 * DIM))[tid] = make_uint4(0,0,0,0);
        return;
    }

    __shared__ float part0[4][DIM], part1[4][DIM];
    __shared__ unsigned int cnt_s[2][4];
    __shared__ float nred[2][4];

    float a0=0.f,a1=0.f,a2=0.f,a3=0.f;   // class c0 accum
    float b0=0.f,b1=0.f,b2=0.f,b3=0.f;   // class c1 accum
    unsigned int n0 = 0, n1 = 0;

    for (int it = 0; it < NROWS / 256 / 8; ++it) {
        int lb[8];
        #pragma unroll
        for (int u = 0; u < 8; ++u)
            lb[u] = labels[(it * 8 + u) * 256 + wave * 64 + lane];
        #pragma unroll
        for (int u = 0; u < 8; ++u) {
            unsigned long long m0 = __ballot(lb[u] == c0);
            unsigned long long m1 = __ballot(lb[u] == c1);
            n0 += (unsigned int)__popcll(m0);
            n1 += (unsigned int)__popcll(m1);
            int rb = (it * 8 + u) * 256 + wave * 64;
            while (m0) {
                int b = __ffsll((long long)m0) - 1;  m0 &= m0 - 1;
                ushort4 v = ((const ushort4*)(e + (size_t)(rb + b) * DIM))[lane];
                a0 += bf2f(v.x); a1 += bf2f(v.y); a2 += bf2f(v.z); a3 += bf2f(v.w);
            }
            while (m1) {
                int b = __ffsll((long long)m1) - 1;  m1 &= m1 - 1;
                ushort4 v = ((const ushort4*)(e + (size_t)(rb + b) * DIM))[lane];
                b0 += bf2f(v.x); b1 += bf2f(v.y); b2 += bf2f(v.z); b3 += bf2f(v.w);
            }
        }
    }
    ((float4*)part0[wave])[lane] = make_float4(a0, a1, a2, a3);
    ((float4*)part1[wave])[lane] = make_float4(b0, b1, b2, b3);
    if (lane == 0) { cnt_s[0][wave] = n0; cnt_s[1][wave] = n1; }
    __syncthreads();

    // 256 threads: dim tid for each class
    float s0 = part0[0][tid] + part0[1][tid] + part0[2][tid] + part0[3][tid];
    float s1 = part1[0][tid] + part1[1][tid] + part1[2][tid] + part1[3][tid];
    float f0 = (float)(cnt_s[0][0] + cnt_s[0][1] + cnt_s[0][2] + cnt_s[0][3]);
    float f1 = (float)(cnt_s[1][0] + cnt_s[1][1] + cnt_s[1][2] + cnt_s[1][3]);
    float v0 = s0 * (1.0f / fmaxf(f0, 1.0f));
    float v1 = s1 * (1.0f / fmaxf(f1, 1.0f));
    float q0 = v0 * v0, q1 = v1 * v1;
    #pragma unroll
    for (int off = 32; off >= 1; off >>= 1) {
        q0 += __shfl_xor(q0, off);
        q1 += __shfl_xor(q1, off);
    }
    if (lane == 0) { nred[0][wave] = q0; nred[1][wave] = q1; }
    __syncthreads();
    float t0 = nred[0][0] + nred[0][1] + nred[0][2] + nred[0][3];
    float t1 = nred[1][0] + nred[1][1] + nred[1][2] + nred[1][3];
    cs[(size_t)c0 * DIM + tid] = f2bf(v0 * (1.0f / fmaxf(sqrtf(t0), 1e-8f)));
    cs[(size_t)c1 * DIM + tid] = f2bf(v1 * (1.0f / fmaxf(sqrtf(t1), 1e-8f)));
}

// K3: bf16 MFMA GEMM-BT + fused loss + fused finalization (R8, unchanged).
// A kc=0,1 in LDS (32 KB); A kc=2,3 in 64 VGPRs, ALL indices compile-time
// (runtime-indexed reg arrays spill to scratch — R7 lesson). B glds
// double-buffered; one barrier per step. LDS 64 KB -> 2 blocks/CU.
#define TMB 128
#define TCB 128

__global__ __launch_bounds__(256, 2) void k_loss_mfma(
    const unsigned short* __restrict__ e, const unsigned short* __restrict__ cs,
    const int* __restrict__ labels, float* __restrict__ acc,
    unsigned int* __restrict__ done, float* __restrict__ out)
{
    __shared__ __align__(16) unsigned short a_s[2][TMB * 64];  // 32 KB
    __shared__ __align__(16) unsigned short b_s[2][TCB * 64];  // 32 KB
    __shared__ float red_s[4];

    const int tid  = threadIdx.x;
    const int row0 = blockIdx.x * TMB;
    const int wave = tid >> 6, lane = tid & 63;
    const int wm = wave >> 1, wn = wave & 1;   // 2x2 wave grid, 64x64 tiles
    const int l16 = lane & 15, q = lane >> 4;
    const int st_r = lane >> 3;                // staging row within 8-row chunk
    const int st_s = (lane & 7) ^ st_r;        // XOR-swizzled source slice

    int labv[16];
    #pragma unroll
    for (int mi = 0; mi < 4; ++mi)
        #pragma unroll
        for (int rg = 0; rg < 4; ++rg)
            labv[mi * 4 + rg] = labels[row0 + wm*64 + mi*16 + q*4 + rg];

    // stage A kc=0,1 into LDS (8 glds/wave)
    #pragma unroll
    for (int kc = 0; kc < 2; ++kc)
        #pragma unroll
        for (int ch = 0; ch < 4; ++ch) {
            int chunk = wave * 4 + ch;
            int row   = chunk * 8 + st_r;
            gload_lds16(&e[(size_t)(row0 + row) * DIM + kc * 64 + st_s * 8],
                        &a_s[kc][chunk * 512]);
        }
    // A kc=2,3 into registers (plain loads; indices all compile-time)
    bf16x8 af2[4][2], af3[4][2];
    #pragma unroll
    for (int mi = 0; mi < 4; ++mi) {
        const unsigned short* pa =
            e + (size_t)(row0 + wm*64 + mi*16 + l16) * DIM + 128 + q * 8;
        af2[mi][0] = *(const bf16x8*)pa;
        af2[mi][1] = *(const bf16x8*)(pa + 32);
        af3[mi][0] = *(const bf16x8*)(pa + 64);
        af3[mi][1] = *(const bf16x8*)(pa + 96);
    }
    // stage B step 0
    #pragma unroll
    for (int ch = 0; ch < 4; ++ch) {
        int chunk = wave * 4 + ch;
        int row   = chunk * 8 + st_r;
        gload_lds16(&cs[(size_t)row * DIM + st_s * 8], &b_s[0][chunk * 512]);
    }
    __syncthreads();   // drains all preamble glds; A + B(0) visible

    float la_bulk = 0.0f, la_corr = 0.0f;
    const float KN = 1.0f / 999.0f;

    for (int cb = 0; cb < CPAD / TCB; ++cb) {
        f32x4 accf[4][4];
        #pragma unroll
        for (int mi = 0; mi < 4; ++mi)
            #pragma unroll
            for (int ni = 0; ni < 4; ++ni)
                accf[mi][ni] = (f32x4){0.f, 0.f, 0.f, 0.f};

        #pragma unroll
        for (int kc = 0; kc < 4; ++kc) {
            // prefetch next step into buffer (kc+1)&1 (compile-time parity)
            if (cb < 7 || kc < 3) {
                const int cb2 = (kc == 3) ? cb + 1 : cb;
                const int kc2 = (kc + 1) & 3;
                #pragma unroll
                for (int ch = 0; ch < 4; ++ch) {
                    int chunk = wave * 4 + ch;
                    int row   = chunk * 8 + st_r;
                    gload_lds16(&cs[(size_t)(cb2 * TCB + row) * DIM + kc2 * 64 + st_s * 8],
                                &b_s[(kc + 1) & 1][chunk * 512]);
                }
            }
            const unsigned short* bs = b_s[kc & 1];
            #pragma unroll
            for (int kk = 0; kk < 2; ++kk) {
                bf16x8 af[4], bfr[4];
                #pragma unroll
                for (int mi = 0; mi < 4; ++mi) {
                    if (kc == 0 || kc == 1) {
                        int rowA = wm*64 + mi*16 + l16;
                        af[mi] = *(const bf16x8*)&a_s[kc][
                            rowA*64 + (((kk*4 + q) ^ (rowA & 7)) * 8)];
                    } else if (kc == 2) {
                        af[mi] = af2[mi][kk];
                    } else {
                        af[mi] = af3[mi][kk];
                    }
                }
                #pragma unroll
                for (int ni = 0; ni < 4; ++ni) {
                    int rowB = wn*64 + ni*16 + l16;
                    bfr[ni] = *(const bf16x8*)&bs[rowB*64 + (((kk*4 + q) ^ (rowB & 7)) * 8)];
                }
                #pragma unroll
                for (int mi = 0; mi < 4; ++mi)
                    #pragma unroll
                    for (int ni = 0; ni < 4; ++ni)
                        accf[mi][ni] = __builtin_amdgcn_mfma_f32_16x16x32_bf16(
                            af[mi], bfr[ni], accf[mi][ni], 0, 0, 0);
            }
            __syncthreads();   // readers of b_s[kc&1] done; covers prefetch
        }

        // epilogue for this class tile: C/D col = l16, row = q*4 + reg
        #pragma unroll
        for (int mi = 0; mi < 4; ++mi)
            #pragma unroll
            for (int rg = 0; rg < 4; ++rg) {
                #pragma unroll
                for (int ni = 0; ni < 4; ++ni) {
                    float t = 1.0f - accf[mi][ni][rg];
                    la_bulk += t * t;
                }
                int lr = labv[mi*4 + rg] - cb*128 - wn*64 - l16;
                if ((lr & ~48) == 0) {
                    int nih = lr >> 4;
                    float sv = (nih == 0) ? accf[mi][0][rg] :
                               (nih == 1) ? accf[mi][1][rg] :
                               (nih == 2) ? accf[mi][2][rg] : accf[mi][3][rg];
                    float t = 1.0f - sv;
                    la_corr += t * t;
                }
            }
    }

    // block reduction + fused finalization via atomic ticket
    float la = la_bulk * KN + la_corr * (1.0f - KN);
    #pragma unroll
    for (int off = 32; off >= 1; off >>= 1) la += __shfl_xor(la, off);
    if (lane == 0) red_s[wave] = la;
    __syncthreads();
    if (tid == 0) {
        atomicAdd(acc, red_s[0] + red_s[1] + red_s[2] + red_s[3]);
        __threadfence();
        unsigned int t = atomicAdd(done, 1u);
        if (t == (unsigned int)(NROWS / TMB) - 1u) {
            float v = atomicAdd(acc, 0.0f);    // atomic read: all adds visible
            out[0] = v * (1.0f / (float)NROWS) - 24.0f * (1.0f / 999.0f);
        }
    }
}

extern "C" void kernel_launch(void* const* d_in, const int* in_sizes, int n_in,
                              void* d_out, int out_size, void* d_ws, size_t ws_size,
                              hipStream_t stream)
{
    const float* emb    = (const float*)d_in[0];
    const int*   labels = (const int*)d_in[1];
    float*       out    = (float*)d_out;
    char*        ws     = (char*)d_ws;

    const size_t OFF_CS   = (size_t)NROWS * DIM * 2;           // e: 32 MB
    const size_t OFF_ACC  = OFF_CS + (size_t)CPAD * DIM * 2;   // cs: 512 KB
    const size_t OFF_DONE = OFF_ACC + 16;

    unsigned short* e    = (unsigned short*)ws;
    unsigned short* cs   = (unsigned short*)(ws + OFF_CS);
    float*          acc  = (float*)(ws + OFF_ACC);
    unsigned int*   done = (unsigned int*)(ws + OFF_DONE);

    k_norm_acc      <<<NROWS / 32, 256, 0, stream>>>(emb, e, acc, done);
    k_gather_centers<<<CPAD / 2, 256, 0, stream>>>(e, labels, cs);
    k_loss_mfma     <<<NROWS / TMB, 256, 0, stream>>>(e, cs, labels, acc, done, out);
}

// Round 10
// 163.754 us; speedup vs baseline: 1.1175x; 1.1175x over previous
//
#include <hip/hip_runtime.h>
#include <hip/hip_bf16.h>

#define NROWS 65536
#define DIM   256
#define NCLS  1000
#define CPAD  1024

typedef __attribute__((ext_vector_type(8))) short bf16x8;   // 8 bf16 = 4 VGPR
typedef __attribute__((ext_vector_type(4))) float f32x4;    // MFMA C/D

// RTNE float -> bf16 bit pattern (finite inputs only)
__device__ inline unsigned short f2bf(float x) {
    unsigned int u = __builtin_bit_cast(unsigned int, x);
    unsigned int lsb = (u >> 16) & 1u;
    u += 0x7fffu + lsb;
    return (unsigned short)(u >> 16);
}

__device__ inline float bf2f(unsigned short u) {
    unsigned int v = ((unsigned int)u) << 16;
    return __builtin_bit_cast(float, v);
}

// async global->LDS, 16 B per lane, dst = wave-uniform base + lane*16
__device__ inline void gload_lds16(const void* g, void* l) {
    __builtin_amdgcn_global_load_lds(
        (const __attribute__((address_space(1))) unsigned int*)g,
        (__attribute__((address_space(3))) unsigned int*)l, 16, 0, 0);
}

// K1: 8 rows per wave, 4-row batched pipeline (R9). Also zeroes the
// sums/counts/acc/done scratch (stream-ordered before K2 needs it).
__global__ __launch_bounds__(256) void k_norm_acc(
    const float* __restrict__ emb, unsigned short* __restrict__ e,
    float* __restrict__ sums, unsigned int* __restrict__ counts,
    float* __restrict__ acc, unsigned int* __restrict__ done)
{
    const int tid = threadIdx.x;
    const int bid = blockIdx.x;
    // zero scratch: 2048 blocks x 128 floats = CPAD*DIM sums
    if (tid < 128) sums[bid * 128 + tid] = 0.0f;
    if (bid < 16 && tid < 64) counts[bid * 64 + tid] = 0u;   // 1024 counts
    if (bid == 0 && tid == 0) { *acc = 0.0f; *done = 0u; }

    const int wave = tid >> 6, lane = tid & 63;
    const int w = bid * 4 + wave;                 // 8192 waves, 8 rows each

    #pragma unroll
    for (int i = 0; i < 2; ++i) {
        const int rbase = w * 8 + i * 4;
        float4 v[4];
        #pragma unroll
        for (int r = 0; r < 4; ++r)
            v[r] = ((const float4*)(emb + (size_t)(rbase + r) * DIM))[lane];
        float ss[4];
        #pragma unroll
        for (int r = 0; r < 4; ++r)
            ss[r] = v[r].x*v[r].x + v[r].y*v[r].y + v[r].z*v[r].z + v[r].w*v[r].w;
        #pragma unroll
        for (int off = 1; off < 64; off <<= 1) {
            #pragma unroll
            for (int r = 0; r < 4; ++r) ss[r] += __shfl_xor(ss[r], off);
        }
        #pragma unroll
        for (int r = 0; r < 4; ++r) {
            float inv = 1.0f / fmaxf(sqrtf(ss[r]), 1e-12f);
            ushort4 u;
            u.x = f2bf(v[r].x * inv); u.y = f2bf(v[r].y * inv);
            u.z = f2bf(v[r].z * inv); u.w = f2bf(v[r].w * inv);
            ((ushort4*)(e + (size_t)(rbase + r) * DIM))[lane] = u;
        }
    }
}

// K2: partial class sums, 2000 blocks = 1000 classes x 2 row-halves
// (~31 waves/CU: the gather while-loops are latency-bound — R9 proved TLP
// is what they need). Ballot-scan half the labels, wave-cooperative row
// gathers, flush via one fp32 global atomic per dim + one counts atomic.
__global__ __launch_bounds__(256) void k_gather_partial(
    const unsigned short* __restrict__ e, const int* __restrict__ labels,
    float* __restrict__ sums, unsigned int* __restrict__ counts)
{
    const int c   = blockIdx.x >> 1;       // 0..999
    const int h   = blockIdx.x & 1;        // row half
    const int tid = threadIdx.x;
    const int wave = tid >> 6, lane = tid & 63;

    __shared__ float part[4][DIM];
    __shared__ unsigned int cnt_s[4];

    const int base = h * (NROWS / 2);
    float a0 = 0.f, a1 = 0.f, a2 = 0.f, a3 = 0.f;
    unsigned int cnt = 0;

    for (int it = 0; it < (NROWS / 2) / 256 / 8; ++it) {   // 16 iterations
        int lb[8];
        #pragma unroll
        for (int u = 0; u < 8; ++u)
            lb[u] = labels[base + (it * 8 + u) * 256 + wave * 64 + lane];
        #pragma unroll
        for (int u = 0; u < 8; ++u) {
            unsigned long long m = __ballot(lb[u] == c);
            cnt += (unsigned int)__popcll(m);
            int rb = base + (it * 8 + u) * 256 + wave * 64;
            while (m) {
                int b = __ffsll((long long)m) - 1;  m &= m - 1;
                ushort4 v = ((const ushort4*)(e + (size_t)(rb + b) * DIM))[lane];
                a0 += bf2f(v.x); a1 += bf2f(v.y); a2 += bf2f(v.z); a3 += bf2f(v.w);
            }
        }
    }
    ((float4*)part[wave])[lane] = make_float4(a0, a1, a2, a3);
    if (lane == 0) cnt_s[wave] = cnt;
    __syncthreads();

    float s = part[0][tid] + part[1][tid] + part[2][tid] + part[3][tid];
    atomicAdd(&sums[(size_t)c * DIM + tid], s);
    if (tid == 0)
        atomicAdd(&counts[c], cnt_s[0] + cnt_s[1] + cnt_s[2] + cnt_s[3]);
}

// K3: one wave per class (all CPAD): center = sum/max(cnt,1), fold
// 1/max(||c||,1e-8), store bf16. Phantoms: sums=0,counts=0 -> cs=0.
__global__ __launch_bounds__(256) void k_centers(
    const float* __restrict__ sums, const unsigned int* __restrict__ counts,
    unsigned short* __restrict__ cs)
{
    int gid  = blockIdx.x * 256 + threadIdx.x;
    int c    = gid >> 6;          // wave-uniform
    int lane = gid & 63;
    float4 v = ((const float4*)(sums + (size_t)c * DIM))[lane];
    float ic = 1.0f / fmaxf((float)counts[c], 1.0f);
    v.x *= ic; v.y *= ic; v.z *= ic; v.w *= ic;
    float ss = v.x*v.x + v.y*v.y + v.z*v.z + v.w*v.w;
    #pragma unroll
    for (int off = 1; off < 64; off <<= 1) ss += __shfl_xor(ss, off);
    float sc = 1.0f / fmaxf(sqrtf(ss), 1e-8f);
    ushort4 u;
    u.x = f2bf(v.x * sc); u.y = f2bf(v.y * sc);
    u.z = f2bf(v.z * sc); u.w = f2bf(v.w * sc);
    ((ushort4*)(cs + (size_t)c * DIM))[lane] = u;
}

// K4: bf16 MFMA GEMM-BT + fused loss + fused finalization (R8, unchanged).
// A kc=0,1 in LDS (32 KB); A kc=2,3 in 64 VGPRs, ALL indices compile-time
// (runtime-indexed reg arrays spill to scratch — R7 lesson). B glds
// double-buffered; one barrier per step. LDS 64 KB -> 2 blocks/CU.
#define TMB 128
#define TCB 128

__global__ __launch_bounds__(256, 2) void k_loss_mfma(
    const unsigned short* __restrict__ e, const unsigned short* __restrict__ cs,
    const int* __restrict__ labels, float* __restrict__ acc,
    unsigned int* __restrict__ done, float* __restrict__ out)
{
    __shared__ __align__(16) unsigned short a_s[2][TMB * 64];  // 32 KB
    __shared__ __align__(16) unsigned short b_s[2][TCB * 64];  // 32 KB
    __shared__ float red_s[4];

    const int tid  = threadIdx.x;
    const int row0 = blockIdx.x * TMB;
    const int wave = tid >> 6, lane = tid & 63;
    const int wm = wave >> 1, wn = wave & 1;   // 2x2 wave grid, 64x64 tiles
    const int l16 = lane & 15, q = lane >> 4;
    const int st_r = lane >> 3;                // staging row within 8-row chunk
    const int st_s = (lane & 7) ^ st_r;        // XOR-swizzled source slice

    int labv[16];
    #pragma unroll
    for (int mi = 0; mi < 4; ++mi)
        #pragma unroll
        for (int rg = 0; rg < 4; ++rg)
            labv[mi * 4 + rg] = labels[row0 + wm*64 + mi*16 + q*4 + rg];

    // stage A kc=0,1 into LDS (8 glds/wave)
    #pragma unroll
    for (int kc = 0; kc < 2; ++kc)
        #pragma unroll
        for (int ch = 0; ch < 4; ++ch) {
            int chunk = wave * 4 + ch;
            int row   = chunk * 8 + st_r;
            gload_lds16(&e[(size_t)(row0 + row) * DIM + kc * 64 + st_s * 8],
                        &a_s[kc][chunk * 512]);
        }
    // A kc=2,3 into registers (plain loads; indices all compile-time)
    bf16x8 af2[4][2], af3[4][2];
    #pragma unroll
    for (int mi = 0; mi < 4; ++mi) {
        const unsigned short* pa =
            e + (size_t)(row0 + wm*64 + mi*16 + l16) * DIM + 128 + q * 8;
        af2[mi][0] = *(const bf16x8*)pa;
        af2[mi][1] = *(const bf16x8*)(pa + 32);
        af3[mi][0] = *(const bf16x8*)(pa + 64);
        af3[mi][1] = *(const bf16x8*)(pa + 96);
    }
    // stage B step 0
    #pragma unroll
    for (int ch = 0; ch < 4; ++ch) {
        int chunk = wave * 4 + ch;
        int row   = chunk * 8 + st_r;
        gload_lds16(&cs[(size_t)row * DIM + st_s * 8], &b_s[0][chunk * 512]);
    }
    __syncthreads();   // drains all preamble glds; A + B(0) visible

    float la_bulk = 0.0f, la_corr = 0.0f;
    const float KN = 1.0f / 999.0f;

    for (int cb = 0; cb < CPAD / TCB; ++cb) {
        f32x4 accf[4][4];
        #pragma unroll
        for (int mi = 0; mi < 4; ++mi)
            #pragma unroll
            for (int ni = 0; ni < 4; ++ni)
                accf[mi][ni] = (f32x4){0.f, 0.f, 0.f, 0.f};

        #pragma unroll
        for (int kc = 0; kc < 4; ++kc) {
            // prefetch next step into buffer (kc+1)&1 (compile-time parity)
            if (cb < 7 || kc < 3) {
                const int cb2 = (kc == 3) ? cb + 1 : cb;
                const int kc2 = (kc + 1) & 3;
                #pragma unroll
                for (int ch = 0; ch < 4; ++ch) {
                    int chunk = wave * 4 + ch;
                    int row   = chunk * 8 + st_r;
                    gload_lds16(&cs[(size_t)(cb2 * TCB + row) * DIM + kc2 * 64 + st_s * 8],
                                &b_s[(kc + 1) & 1][chunk * 512]);
                }
            }
            const unsigned short* bs = b_s[kc & 1];
            #pragma unroll
            for (int kk = 0; kk < 2; ++kk) {
                bf16x8 af[4], bfr[4];
                #pragma unroll
                for (int mi = 0; mi < 4; ++mi) {
                    if (kc == 0 || kc == 1) {
                        int rowA = wm*64 + mi*16 + l16;
                        af[mi] = *(const bf16x8*)&a_s[kc][
                            rowA*64 + (((kk*4 + q) ^ (rowA & 7)) * 8)];
                    } else if (kc == 2) {
                        af[mi] = af2[mi][kk];
                    } else {
                        af[mi] = af3[mi][kk];
                    }
                }
                #pragma unroll
                for (int ni = 0; ni < 4; ++ni) {
                    int rowB = wn*64 + ni*16 + l16;
                    bfr[ni] = *(const bf16x8*)&bs[rowB*64 + (((kk*4 + q) ^ (rowB & 7)) * 8)];
                }
                #pragma unroll
                for (int mi = 0; mi < 4; ++mi)
                    #pragma unroll
                    for (int ni = 0; ni < 4; ++ni)
                        accf[mi][ni] = __builtin_amdgcn_mfma_f32_16x16x32_bf16(
                            af[mi], bfr[ni], accf[mi][ni], 0, 0, 0);
            }
            __syncthreads();   // readers of b_s[kc&1] done; covers prefetch
        }

        // epilogue for this class tile: C/D col = l16, row = q*4 + reg
        #pragma unroll
        for (int mi = 0; mi < 4; ++mi)
            #pragma unroll
            for (int rg = 0; rg < 4; ++rg) {
                #pragma unroll
                for (int ni = 0; ni < 4; ++ni) {
                    float t = 1.0f - accf[mi][ni][rg];
                    la_bulk += t * t;
                }
                int lr = labv[mi*4 + rg] - cb*128 - wn*64 - l16;
                if ((lr & ~48) == 0) {
                    int nih = lr >> 4;
                    float sv = (nih == 0) ? accf[mi][0][rg] :
                               (nih == 1) ? accf[mi][1][rg] :
                               (nih == 2) ? accf[mi][2][rg] : accf[mi][3][rg];
                    float t = 1.0f - sv;
                    la_corr += t * t;
                }
            }
    }

    // block reduction + fused finalization via atomic ticket
    float la = la_bulk * KN + la_corr * (1.0f - KN);
    #pragma unroll
    for (int off = 32; off >= 1; off >>= 1) la += __shfl_xor(la, off);
    if (lane == 0) red_s[wave] = la;
    __syncthreads();
    if (tid == 0) {
        atomicAdd(acc, red_s[0] + red_s[1] + red_s[2] + red_s[3]);
        __threadfence();
        unsigned int t = atomicAdd(done, 1u);
        if (t == (unsigned int)(NROWS / TMB) - 1u) {
            float v = atomicAdd(acc, 0.0f);    // atomic read: all adds visible
            out[0] = v * (1.0f / (float)NROWS) - 24.0f * (1.0f / 999.0f);
        }
    }
}

extern "C" void kernel_launch(void* const* d_in, const int* in_sizes, int n_in,
                              void* d_out, int out_size, void* d_ws, size_t ws_size,
                              hipStream_t stream)
{
    const float* emb    = (const float*)d_in[0];
    const int*   labels = (const int*)d_in[1];
    float*       out    = (float*)d_out;
    char*        ws     = (char*)d_ws;

    const size_t OFF_CS   = (size_t)NROWS * DIM * 2;            // e: 32 MB
    const size_t OFF_SUMS = OFF_CS + (size_t)CPAD * DIM * 2;    // cs: 512 KB
    const size_t OFF_CNT  = OFF_SUMS + (size_t)CPAD * DIM * 4;  // sums: 1 MB
    const size_t OFF_ACC  = OFF_CNT + (size_t)CPAD * 4;         // counts: 4 KB
    const size_t OFF_DONE = OFF_ACC + 16;

    unsigned short* e      = (unsigned short*)ws;
    unsigned short* cs     = (unsigned short*)(ws + OFF_CS);
    float*          sums   = (float*)(ws + OFF_SUMS);
    unsigned int*   counts = (unsigned int*)(ws + OFF_CNT);
    float*          acc    = (float*)(ws + OFF_ACC);
    unsigned int*   done   = (unsigned int*)(ws + OFF_DONE);

    k_norm_acc      <<<NROWS / 32, 256, 0, stream>>>(emb, e, sums, counts, acc, done);
    k_gather_partial<<<NCLS * 2, 256, 0, stream>>>(e, labels, sums, counts);
    k_centers       <<<CPAD / 4, 256, 0, stream>>>(sums, counts, cs);
    k_loss_mfma     <<<NROWS / TMB, 256, 0, stream>>>(e, cs, labels, acc, done, out);
}